// Round 1
// baseline (1728.757 us; speedup 1.0000x reference)
//
#include <hip/hip_runtime.h>

#define HH 56
#define WW 56
#define CC 512
#define BB 32
#define LL (HH*WW)
#define MM (BB*LL)     // 100352 tokens
#define HID 2048

typedef __attribute__((ext_vector_type(8))) __bf16 bf16x8;
typedef __attribute__((ext_vector_type(4))) float f32x4;

__device__ __forceinline__ short f2bf(float f) {
    union { float f; unsigned u; } c; c.f = f;
    unsigned r = c.u + 0x7fffu + ((c.u >> 16) & 1u);   // round-to-nearest-even
    return (short)(r >> 16);
}
__device__ __forceinline__ float bf2f(short s) {
    union { unsigned u; float f; } c; c.u = ((unsigned)(unsigned short)s) << 16;
    return c.f;
}

// ---------------- f32 -> bf16 weight conversion ----------------
__global__ __launch_bounds__(256) void cvt_bf16(const float* __restrict__ in,
                                                short* __restrict__ out, int n) {
    int i = blockIdx.x * 256 + threadIdx.x;
    if (i < n) out[i] = f2bf(in[i]);
}

// ---------------- LayerNorm over 512 channels, 1 row / block ----------------
__global__ __launch_bounds__(256) void ln512(const float* __restrict__ x,
                                             const float* __restrict__ g,
                                             const float* __restrict__ b,
                                             short* __restrict__ out) {
    const int row = blockIdx.x;
    const int t = threadIdx.x;
    const float2 v = ((const float2*)(x + (long)row * 512))[t];
    float s = v.x + v.y;
    float q = v.x * v.x + v.y * v.y;
#pragma unroll
    for (int off = 32; off > 0; off >>= 1) {
        s += __shfl_xor(s, off, 64);
        q += __shfl_xor(q, off, 64);
    }
    __shared__ float red[8];
    const int wv = t >> 6;
    if ((t & 63) == 0) { red[wv] = s; red[4 + wv] = q; }
    __syncthreads();
    s = red[0] + red[1] + red[2] + red[3];
    q = red[4] + red[5] + red[6] + red[7];
    const float mu = s * (1.0f / 512.0f);
    const float rs = rsqrtf(q * (1.0f / 512.0f) - mu * mu + 1e-5f);
    const float2 gv = ((const float2*)g)[t];
    const float2 bv = ((const float2*)b)[t];
    const float y0 = (v.x - mu) * rs * gv.x + bv.x;
    const float y1 = (v.y - mu) * rs * gv.y + bv.y;
    union { short s2[2]; unsigned u; } o;
    o.s2[0] = f2bf(y0); o.s2[1] = f2bf(y1);
    ((unsigned*)out)[(long)row * 256 + t] = o.u;
}

// ---------------- spatial (window) MLP + residual ----------------
// block = (8 windows, 1 head); lane owns (window, channel); x values in VGPRs,
// spatial_w read via wave-uniform addresses (scalar loads).
__global__ __launch_bounds__(256) void spatial_mlp(const short* __restrict__ xn,
                                                   const float* __restrict__ x,
                                                   const float* __restrict__ sw,
                                                   const float* __restrict__ sb,
                                                   float* x1) {
    const int head = blockIdx.y;
    const int t = threadIdx.x;
    const int ch = t & 31;
    const int wloc = t >> 5;
    const int win = blockIdx.x * 8 + wloc;        // 0..2591
    const int b = win / 81;
    const int rr = win - b * 81;
    const int wi = rr / 9;
    const int wj = rr - wi * 9;
    const int c = head * 32 + ch;

    // load the 49 (possibly zero-padded) window inputs into registers
    float xv[49];
#pragma unroll
    for (int j = 0; j < 49; j++) {
        const int pr = wi * 7 + j / 7 - 4;        // padded row - P_T
        const int pc = wj * 7 + j % 7 - 4;        // padded col - P_L
        float v = 0.0f;
        if (pr >= 0 && pr < 56 && pc >= 0 && pc < 56)
            v = bf2f(xn[((long)((b * 56 + pr) * 56 + pc)) * 512 + c]);
        xv[j] = v;
    }

    const float* swh = sw + head * 2401;
    const float* sbh = sb + head * 49;

#pragma unroll 1
    for (int t7 = 0; t7 < 7; t7++) {
        float acc[7];
#pragma unroll
        for (int ii = 0; ii < 7; ii++) acc[ii] = sbh[t7 * 7 + ii];
#pragma unroll
        for (int ii = 0; ii < 7; ii++) {
            const float* swr = swh + (t7 * 7 + ii) * 49;
#pragma unroll
            for (int j = 0; j < 49; j++)
                acc[ii] = fmaf(swr[j], xv[j], acc[ii]);
        }
        // i = t7*7+ii  ->  i/7 = t7, i%7 = ii
        const int pr = wi * 7 + t7 - 4;
        if (pr >= 0 && pr < 56) {
#pragma unroll
            for (int ii = 0; ii < 7; ii++) {
                const int pc = wj * 7 + ii - 4;
                if (pc >= 0 && pc < 56) {
                    const long idx = ((long)((b * 56 + pr) * 56 + pc)) * 512 + c;
                    x1[idx] = x[idx] + acc[ii];
                }
            }
        }
    }
}

// ---------------- bf16 GEMM, A[M,K] row-major, Bw[N,K] row-major (B^T) -------
// 128x128 tile, 4 waves (2x2), 4x4 fragments of 16x16x32 bf16 MFMA, BK=32,
// global_load_lds width-16 staging, 2-barrier K-loop (m97 structure).
template <int K, int N, bool GELU>
__global__ __launch_bounds__(256) void gemm_bt(const short* __restrict__ A,
                                               const short* __restrict__ Bw,
                                               const float* __restrict__ bias,
                                               const float* res,
                                               void* Cout) {
    __shared__ __attribute__((aligned(16))) short As[128 * 32];
    __shared__ __attribute__((aligned(16))) short Bs[128 * 32];
    const int t = threadIdx.x;
    const int lane = t & 63;
    const int w = t >> 6;
    const int wr = w >> 1, wc = w & 1;
    const long mBase = (long)blockIdx.x * 128;
    const long nBase = (long)blockIdx.y * 128;
    const int lr = lane & 15;
    const int kg = lane >> 4;

    f32x4 acc[4][4] = {};

    for (int k0 = 0; k0 < K; k0 += 32) {
        __syncthreads();                      // all waves done reading prev tile
        const short* Ab = A + mBase * K + k0;
        const short* Bb = Bw + nBase * K + k0;
#pragma unroll
        for (int p = 0; p < 2; p++) {
            const int q = p * 256 + t;        // 16B chunk id, 512 per tile
            const int row = q >> 2;
            const int kc = (q & 3) << 3;
            __builtin_amdgcn_global_load_lds(
                (const __attribute__((address_space(1))) void*)(Ab + (long)row * K + kc),
                (__attribute__((address_space(3))) void*)((char*)As + (p * 256 + w * 64) * 16),
                16, 0, 0);
            __builtin_amdgcn_global_load_lds(
                (const __attribute__((address_space(1))) void*)(Bb + (long)row * K + kc),
                (__attribute__((address_space(3))) void*)((char*)Bs + (p * 256 + w * 64) * 16),
                16, 0, 0);
        }
        __syncthreads();                      // staging complete (vmcnt drained)

        bf16x8 af[4], bfv[4];
#pragma unroll
        for (int m = 0; m < 4; m++)
            af[m] = *(const bf16x8*)&As[(wr * 64 + m * 16 + lr) * 32 + kg * 8];
#pragma unroll
        for (int n = 0; n < 4; n++)
            bfv[n] = *(const bf16x8*)&Bs[(wc * 64 + n * 16 + lr) * 32 + kg * 8];
#pragma unroll
        for (int m = 0; m < 4; m++)
#pragma unroll
            for (int n = 0; n < 4; n++)
                acc[m][n] = __builtin_amdgcn_mfma_f32_16x16x32_bf16(af[m], bfv[n],
                                                                    acc[m][n], 0, 0, 0);
    }

    // epilogue: C/D layout col = lane&15, row = (lane>>4)*4 + reg
#pragma unroll
    for (int n = 0; n < 4; n++) {
        const long col = nBase + wc * 64 + n * 16 + lr;
        const float bv = bias[col];
#pragma unroll
        for (int m = 0; m < 4; m++) {
#pragma unroll
            for (int r = 0; r < 4; r++) {
                const long row = mBase + wr * 64 + m * 16 + kg * 4 + r;
                float v = acc[m][n][r] + bv;
                const long idx = row * N + col;
                if (GELU) {
                    v = 0.5f * v * (1.0f + erff(v * 0.70710678118f));
                    ((short*)Cout)[idx] = f2bf(v);
                } else {
                    ((float*)Cout)[idx] = res[idx] + v;
                }
            }
        }
    }
}

extern "C" void kernel_launch(void* const* d_in, const int* in_sizes, int n_in,
                              void* d_out, int out_size, void* d_ws, size_t ws_size,
                              hipStream_t stream) {
    const float* x    = (const float*)d_in[0];
    const float* n1g  = (const float*)d_in[1];
    const float* n1b  = (const float*)d_in[2];
    const float* sw   = (const float*)d_in[3];
    const float* sb   = (const float*)d_in[4];
    const float* n2g  = (const float*)d_in[5];
    const float* n2b  = (const float*)d_in[6];
    const float* fc1w = (const float*)d_in[7];
    const float* fc1b = (const float*)d_in[8];
    const float* fc2w = (const float*)d_in[9];
    const float* fc2b = (const float*)d_in[10];
    float* out = (float*)d_out;

    // workspace layout (bytes)
    char* ws = (char*)d_ws;
    short* xn  = (short*)ws;                      // MM*512*2    = 102,760,448  (xn, then xn2)
    short* hb  = (short*)(ws + 102760448);        // MM*2048*2   = 411,041,792
    short* w1b = (short*)(ws + 513802240);        // 2048*512*2  =   2,097,152
    short* w2b = (short*)(ws + 515899392);        // 512*2048*2  =   2,097,152

    cvt_bf16<<<4096, 256, 0, stream>>>(fc1w, w1b, 2048 * 512);
    cvt_bf16<<<4096, 256, 0, stream>>>(fc2w, w2b, 512 * 2048);

    // LN1: x -> xn (bf16)
    ln512<<<MM, 256, 0, stream>>>(x, n1g, n1b, xn);

    // spatial MLP + residual: x1 = x + y  (into d_out)
    spatial_mlp<<<dim3(324, 16), 256, 0, stream>>>(xn, x, sw, sb, out);

    // LN2: x1 -> xn2 (bf16, reuse xn buffer)
    ln512<<<MM, 256, 0, stream>>>(out, n2g, n2b, xn);

    // FC1 + gelu -> h (bf16)
    gemm_bt<512, 2048, true><<<dim3(784, 16), 256, 0, stream>>>(xn, w1b, fc1b, nullptr, hb);

    // FC2 + bias + residual -> out (f32, reads x1 from d_out in place)
    gemm_bt<2048, 512, false><<<dim3(784, 4), 256, 0, stream>>>(hb, w2b, fc2b, out, out);
}

// Round 2
// 1493.149 us; speedup vs baseline: 1.1578x; 1.1578x over previous
//
#include <hip/hip_runtime.h>

#define HH 56
#define WW 56
#define CC 512
#define BB 32
#define LL (HH*WW)
#define MM (BB*LL)     // 100352 tokens
#define HID 2048

typedef __attribute__((ext_vector_type(8))) __bf16 bf16x8;
typedef __attribute__((ext_vector_type(4))) float f32x4;

__device__ __forceinline__ short f2bf(float f) {
    union { float f; unsigned u; } c; c.f = f;
    unsigned r = c.u + 0x7fffu + ((c.u >> 16) & 1u);   // round-to-nearest-even
    return (short)(r >> 16);
}
__device__ __forceinline__ float bf2f(short s) {
    union { unsigned u; float f; } c; c.u = ((unsigned)(unsigned short)s) << 16;
    return c.f;
}

// ---------------- f32 -> bf16 weight conversion ----------------
__global__ __launch_bounds__(256) void cvt_bf16(const float* __restrict__ in,
                                                short* __restrict__ out, int n) {
    int i = blockIdx.x * 256 + threadIdx.x;
    if (i < n) out[i] = f2bf(in[i]);
}

// ---------------- LayerNorm over 512 channels, 1 row / block ----------------
__global__ __launch_bounds__(256) void ln512(const float* __restrict__ x,
                                             const float* __restrict__ g,
                                             const float* __restrict__ b,
                                             short* __restrict__ out) {
    const int row = blockIdx.x;
    const int t = threadIdx.x;
    const float2 v = ((const float2*)(x + (long)row * 512))[t];
    float s = v.x + v.y;
    float q = v.x * v.x + v.y * v.y;
#pragma unroll
    for (int off = 32; off > 0; off >>= 1) {
        s += __shfl_xor(s, off, 64);
        q += __shfl_xor(q, off, 64);
    }
    __shared__ float red[8];
    const int wv = t >> 6;
    if ((t & 63) == 0) { red[wv] = s; red[4 + wv] = q; }
    __syncthreads();
    s = red[0] + red[1] + red[2] + red[3];
    q = red[4] + red[5] + red[6] + red[7];
    const float mu = s * (1.0f / 512.0f);
    const float rs = rsqrtf(q * (1.0f / 512.0f) - mu * mu + 1e-5f);
    const float2 gv = ((const float2*)g)[t];
    const float2 bv = ((const float2*)b)[t];
    const float y0 = (v.x - mu) * rs * gv.x + bv.x;
    const float y1 = (v.y - mu) * rs * gv.y + bv.y;
    union { short s2[2]; unsigned u; } o;
    o.s2[0] = f2bf(y0); o.s2[1] = f2bf(y1);
    ((unsigned*)out)[(long)row * 256 + t] = o.u;
}

// ---------------- spatial (window) MLP + residual ----------------
__global__ __launch_bounds__(256) void spatial_mlp(const short* __restrict__ xn,
                                                   const float* __restrict__ x,
                                                   const float* __restrict__ sw,
                                                   const float* __restrict__ sb,
                                                   float* x1) {
    const int head = blockIdx.y;
    const int t = threadIdx.x;
    const int ch = t & 31;
    const int wloc = t >> 5;
    const int win = blockIdx.x * 8 + wloc;        // 0..2591
    const int b = win / 81;
    const int rr = win - b * 81;
    const int wi = rr / 9;
    const int wj = rr - wi * 9;
    const int c = head * 32 + ch;

    float xv[49];
#pragma unroll
    for (int j = 0; j < 49; j++) {
        const int pr = wi * 7 + j / 7 - 4;        // padded row - P_T
        const int pc = wj * 7 + j % 7 - 4;        // padded col - P_L
        float v = 0.0f;
        if (pr >= 0 && pr < 56 && pc >= 0 && pc < 56)
            v = bf2f(xn[((long)((b * 56 + pr) * 56 + pc)) * 512 + c]);
        xv[j] = v;
    }

    const float* swh = sw + head * 2401;
    const float* sbh = sb + head * 49;

#pragma unroll 1
    for (int t7 = 0; t7 < 7; t7++) {
        float acc[7];
#pragma unroll
        for (int ii = 0; ii < 7; ii++) acc[ii] = sbh[t7 * 7 + ii];
#pragma unroll
        for (int ii = 0; ii < 7; ii++) {
            const float* swr = swh + (t7 * 7 + ii) * 49;
#pragma unroll
            for (int j = 0; j < 49; j++)
                acc[ii] = fmaf(swr[j], xv[j], acc[ii]);
        }
        const int pr = wi * 7 + t7 - 4;
        if (pr >= 0 && pr < 56) {
#pragma unroll
            for (int ii = 0; ii < 7; ii++) {
                const int pc = wj * 7 + ii - 4;
                if (pc >= 0 && pc < 56) {
                    const long idx = ((long)((b * 56 + pr) * 56 + pc)) * 512 + c;
                    x1[idx] = x[idx] + acc[ii];
                }
            }
        }
    }
}

// ---------------- bf16 GEMM, A[M,K] row-major, Bw[N,K] row-major (B^T) -------
// 128x128 tile, 4 waves (2x2), 4x4 fragments of 16x16x32 bf16 MFMA, BK=32,
// DOUBLE-BUFFERED global_load_lds staging (T3 minimum 2-phase):
//   issue next tile's loads BEFORE computing current tile; one
//   vmcnt(0)+barrier (__syncthreads) per iteration.
// Grid: blockIdx.x = N-strip (fast-varying -> consecutive blocks share A-tile),
//       blockIdx.y = M-strip.
template <int K, int N, bool GELU>
__global__ __launch_bounds__(256) void gemm_bt(const short* __restrict__ A,
                                               const short* __restrict__ Bw,
                                               const float* __restrict__ bias,
                                               const float* res,
                                               void* Cout) {
    __shared__ __attribute__((aligned(16))) short As[2][128 * 32];
    __shared__ __attribute__((aligned(16))) short Bs[2][128 * 32];
    const int t = threadIdx.x;
    const int lane = t & 63;
    const int w = t >> 6;
    const int wr = w >> 1, wc = w & 1;
    const long mBase = (long)blockIdx.y * 128;
    const long nBase = (long)blockIdx.x * 128;
    const int lr = lane & 15;
    const int kg = lane >> 4;

    f32x4 acc[4][4] = {};

    // stage K-tile `it` into buffer `buf`
    auto stage = [&](int buf, int it) {
        const long k0 = (long)it * 32;
        const short* Ab = A + mBase * K + k0;
        const short* Bb = Bw + nBase * K + k0;
#pragma unroll
        for (int p = 0; p < 2; p++) {
            const int q = p * 256 + t;        // 16B chunk id, 512 per tile
            const int row = q >> 2;
            const int kc = (q & 3) << 3;
            __builtin_amdgcn_global_load_lds(
                (const __attribute__((address_space(1))) void*)(Ab + (long)row * K + kc),
                (__attribute__((address_space(3))) void*)((char*)&As[buf][0] + (p * 256 + w * 64) * 16),
                16, 0, 0);
            __builtin_amdgcn_global_load_lds(
                (const __attribute__((address_space(1))) void*)(Bb + (long)row * K + kc),
                (__attribute__((address_space(3))) void*)((char*)&Bs[buf][0] + (p * 256 + w * 64) * 16),
                16, 0, 0);
        }
    };

    const int NT = K / 32;
    stage(0, 0);
    __syncthreads();                          // vmcnt(0): tile 0 landed
    int cur = 0;
    for (int it = 0; it < NT; ++it) {
        if (it + 1 < NT) stage(cur ^ 1, it + 1);   // issue next tile (in flight)

        bf16x8 af[4], bfv[4];
#pragma unroll
        for (int m = 0; m < 4; m++)
            af[m] = *(const bf16x8*)&As[cur][(wr * 64 + m * 16 + lr) * 32 + kg * 8];
#pragma unroll
        for (int n = 0; n < 4; n++)
            bfv[n] = *(const bf16x8*)&Bs[cur][(wc * 64 + n * 16 + lr) * 32 + kg * 8];
#pragma unroll
        for (int m = 0; m < 4; m++)
#pragma unroll
            for (int n = 0; n < 4; n++)
                acc[m][n] = __builtin_amdgcn_mfma_f32_16x16x32_bf16(af[m], bfv[n],
                                                                    acc[m][n], 0, 0, 0);

        __syncthreads();                      // vmcnt(0): next tile landed; all
        cur ^= 1;                             // waves done reading buf[cur]
    }

    // epilogue: C/D layout col = lane&15, row = (lane>>4)*4 + reg
#pragma unroll
    for (int n = 0; n < 4; n++) {
        const long col = nBase + wc * 64 + n * 16 + lr;
        const float bv = bias[col];
#pragma unroll
        for (int m = 0; m < 4; m++) {
#pragma unroll
            for (int r = 0; r < 4; r++) {
                const long row = mBase + wr * 64 + m * 16 + kg * 4 + r;
                float v = acc[m][n][r] + bv;
                const long idx = row * N + col;
                if (GELU) {
                    v = 0.5f * v * (1.0f + erff(v * 0.70710678118f));
                    ((short*)Cout)[idx] = f2bf(v);
                } else {
                    ((float*)Cout)[idx] = res[idx] + v;
                }
            }
        }
    }
}

extern "C" void kernel_launch(void* const* d_in, const int* in_sizes, int n_in,
                              void* d_out, int out_size, void* d_ws, size_t ws_size,
                              hipStream_t stream) {
    const float* x    = (const float*)d_in[0];
    const float* n1g  = (const float*)d_in[1];
    const float* n1b  = (const float*)d_in[2];
    const float* sw   = (const float*)d_in[3];
    const float* sb   = (const float*)d_in[4];
    const float* n2g  = (const float*)d_in[5];
    const float* n2b  = (const float*)d_in[6];
    const float* fc1w = (const float*)d_in[7];
    const float* fc1b = (const float*)d_in[8];
    const float* fc2w = (const float*)d_in[9];
    const float* fc2b = (const float*)d_in[10];
    float* out = (float*)d_out;

    // workspace layout (bytes)
    char* ws = (char*)d_ws;
    short* xn  = (short*)ws;                      // MM*512*2    = 102,760,448  (xn, then xn2)
    short* hb  = (short*)(ws + 102760448);        // MM*2048*2   = 411,041,792
    short* w1b = (short*)(ws + 513802240);        // 2048*512*2  =   2,097,152
    short* w2b = (short*)(ws + 515899392);        // 512*2048*2  =   2,097,152

    cvt_bf16<<<4096, 256, 0, stream>>>(fc1w, w1b, 2048 * 512);
    cvt_bf16<<<4096, 256, 0, stream>>>(fc2w, w2b, 512 * 2048);

    // LN1: x -> xn (bf16)
    ln512<<<MM, 256, 0, stream>>>(x, n1g, n1b, xn);

    // spatial MLP + residual: x1 = x + y  (into d_out)
    spatial_mlp<<<dim3(324, 16), 256, 0, stream>>>(xn, x, sw, sb, out);

    // LN2: x1 -> xn2 (bf16, reuse xn buffer)
    ln512<<<MM, 256, 0, stream>>>(out, n2g, n2b, xn);

    // FC1 + gelu -> h (bf16)   grid: x = N-strips (16), y = M-strips (784)
    gemm_bt<512, 2048, true><<<dim3(16, 784), 256, 0, stream>>>(xn, w1b, fc1b, nullptr, hb);

    // FC2 + bias + residual -> out (f32, reads x1 from d_out in place)
    gemm_bt<2048, 512, false><<<dim3(4, 784), 256, 0, stream>>>(hb, w2b, fc2b, out, out);
}